// Round 3
// baseline (470.745 us; speedup 1.0000x reference)
//
#include <hip/hip_runtime.h>
#include <stdint.h>

typedef __attribute__((ext_vector_type(8))) short short8;
typedef __attribute__((ext_vector_type(4))) float float4v;

__device__ __forceinline__ unsigned short f2b(float f){
  unsigned int x = __float_as_uint(f);
  x += 0x7fffu + ((x >> 16) & 1u);
  return (unsigned short)(x >> 16);
}
__device__ __forceinline__ unsigned int pk2(float lo, float hi){
  return (unsigned int)f2b(lo) | ((unsigned int)f2b(hi) << 16);
}
__device__ __forceinline__ float b2f(unsigned short b){
  return __uint_as_float(((unsigned int)b) << 16);
}
__device__ __forceinline__ float silu_f(float x){ return x / (1.0f + __expf(-x)); }
__device__ __forceinline__ float cutoff_f(float d){
  float c = 0.5f * (__cosf(d * 0.62831853071795864f) + 1.0f);
  return (d < 5.0f) ? c : 0.0f;
}

__device__ __forceinline__ void gl_lds16(const unsigned short* g, unsigned short* l){
  __builtin_amdgcn_global_load_lds(
      (const __attribute__((address_space(1))) unsigned int*)g,
      (__attribute__((address_space(3))) unsigned int*)l, 16, 0, 0);
}

// ---------------- MFMA GEMM core: 128x128 tile, K=512, A,B bf16 [row][k] ld=512.
// BK=64 per barrier-pair (8 iters), staged as 2 sub-buffers of 8KB per matrix,
// each with 64B row stride + XOR k-chunk swizzle (2-way bank alias = free).
__device__ __forceinline__ void gemm_core_b(const unsigned short* __restrict__ A,
                                            const unsigned short* __restrict__ Bt,
                                            int rbase, int cbase, float4v acc[4][4])
{
  __shared__ __align__(16) unsigned short Ash[2*128*32];
  __shared__ __align__(16) unsigned short Bsh[2*128*32];
  const int t = threadIdx.x;
  const int lane = t & 63, wv = t >> 6;
  const int wr = wv >> 1, wc = wv & 1;
  const int lr = lane & 15, lk = lane >> 4;

  // staging: per callsite, thread byte-off = wv*1024 + lane*16 within 4KB (64 rows)
  const int off0 = (wv << 10) + (lane << 4);
  const int row0 = off0 >> 6;                 // 0..63
  const int slot = (off0 >> 4) & 3;
  const int kc   = slot ^ ((row0 >> 1) & 3);  // global k-chunk for this LDS slot
  const unsigned short* ag0 = A  + (size_t)(rbase + row0) * 512 + kc * 8;
  const unsigned short* bg0 = Bt + (size_t)(cbase + row0) * 512 + kc * 8;
  unsigned short* as0 = Ash + (off0 >> 1);
  unsigned short* bs0 = Bsh + (off0 >> 1);

  const int ra = wr * 64 + lr, sa = (ra >> 1) & 3;
  const int rb = wc * 64 + lr, sb = (rb >> 1) & 3;
  const unsigned short* afp = Ash + ra * 32 + ((lk ^ sa) << 3);
  const unsigned short* bfp = Bsh + rb * 32 + ((lk ^ sb) << 3);

  for (int kk = 0; kk < 512; kk += 64) {
    __syncthreads();
    // half 0: k in [kk, kk+32)
    gl_lds16(ag0 + kk,              as0);
    gl_lds16(ag0 + kk + 64*512,     as0 + 2048);
    gl_lds16(bg0 + kk,              bs0);
    gl_lds16(bg0 + kk + 64*512,     bs0 + 2048);
    // half 1: k in [kk+32, kk+64)
    gl_lds16(ag0 + kk + 32,          as0 + 4096);
    gl_lds16(ag0 + kk + 32 + 64*512, as0 + 6144);
    gl_lds16(bg0 + kk + 32,          bs0 + 4096);
    gl_lds16(bg0 + kk + 32 + 64*512, bs0 + 6144);
    __syncthreads();
#pragma unroll
    for (int h = 0; h < 2; ++h) {
      short8 af[4], bf[4];
      const unsigned short* ah = afp + h * 4096;
      const unsigned short* bh = bfp + h * 4096;
#pragma unroll
      for (int f = 0; f < 4; ++f) af[f] = *(const short8*)(ah + f * 512);
#pragma unroll
      for (int f = 0; f < 4; ++f) bf[f] = *(const short8*)(bh + f * 512);
#pragma unroll
      for (int fr = 0; fr < 4; ++fr)
#pragma unroll
        for (int fc = 0; fc < 4; ++fc)
          acc[fr][fc] = __builtin_amdgcn_mfma_f32_16x16x32_bf16(af[fr], bf[fc], acc[fr][fc], 0, 0, 0);
    }
  }
}

// ---------------- generic linear: out = A@W (+ rowscale*bias)
__global__ __launch_bounds__(256, 4) void gemm_lin(const unsigned short* __restrict__ A,
    const unsigned short* __restrict__ Bt, const float* __restrict__ bias,
    const float* __restrict__ rowscale, float* __restrict__ out, int ldc, int nct)
{
  int b = blockIdx.x;
  int ct = b % nct, rt = b / nct;
  int rbase = rt * 128, cbase = ct * 128;
  float4v acc[4][4];
#pragma unroll
  for (int fr = 0; fr < 4; ++fr)
#pragma unroll
    for (int fc = 0; fc < 4; ++fc) acc[fr][fc] = (float4v){0.f,0.f,0.f,0.f};
  gemm_core_b(A, Bt, rbase, cbase, acc);

  const int t = threadIdx.x;
  const int lane = t & 63, wv = t >> 6;
  const int wr = wv >> 1, wc = wv & 1;
  const int lr = lane & 15, lk = lane >> 4;
#pragma unroll
  for (int fr = 0; fr < 4; ++fr)
#pragma unroll
    for (int i = 0; i < 4; ++i) {
      int grow = rbase + wr * 64 + fr * 16 + lk * 4 + i;
      float rs = rowscale ? rowscale[grow] : 1.0f;
#pragma unroll
      for (int fc = 0; fc < 4; ++fc) {
        int col = cbase + wc * 64 + fc * 16 + lr;
        float vv = acc[fr][fc][i];
        if (bias) vv += rs * bias[col];
        out[(size_t)grow * ldc + col] = vv;
      }
    }
}

// ---------------- fused qkv GEMM: out[256][1536] = x @ [Wq|Wk|Wv] + [bq|bk|bv]
// epilogue also computes ksum[h][n] = sum_d k[n][h*64+d]
__global__ __launch_bounds__(256, 4) void gemm_qkv(const unsigned short* __restrict__ A,
    const unsigned short* __restrict__ Bt, const float* __restrict__ bq,
    const float* __restrict__ bk, const float* __restrict__ bv,
    float* __restrict__ out, float* __restrict__ ksum)
{
  int b = blockIdx.x;
  int ct = b % 12, rt = b / 12;
  int rbase = rt * 128, cbase = ct * 128;
  float4v acc[4][4];
#pragma unroll
  for (int fr = 0; fr < 4; ++fr)
#pragma unroll
    for (int fc = 0; fc < 4; ++fc) acc[fr][fc] = (float4v){0.f,0.f,0.f,0.f};
  gemm_core_b(A, Bt, rbase, cbase, acc);

  const int t = threadIdx.x;
  const int lane = t & 63, wv = t >> 6;
  const int wr = wv >> 1, wc = wv & 1;
  const int lr = lane & 15, lk = lane >> 4;

  float bvv[4];
#pragma unroll
  for (int fc = 0; fc < 4; ++fc) {
    int col = cbase + wc * 64 + fc * 16 + lr;
    bvv[fc] = (col < 512) ? bq[col] : (col < 1024 ? bk[col - 512] : bv[col - 1024]);
  }
  bool isk = (cbase >= 512) && (cbase < 1024);
  int h = ((cbase - 512) >> 6) + wc;
#pragma unroll
  for (int fr = 0; fr < 4; ++fr)
#pragma unroll
    for (int i = 0; i < 4; ++i) {
      int grow = rbase + wr * 64 + fr * 16 + lk * 4 + i;
      float s = 0.f;
#pragma unroll
      for (int fc = 0; fc < 4; ++fc) {
        int col = cbase + wc * 64 + fc * 16 + lr;
        float vv = acc[fr][fc][i] + bvv[fc];
        out[(size_t)grow * 1536 + col] = vv;
        s += vv;
      }
      if (isk) {
        s += __shfl_xor(s, 1); s += __shfl_xor(s, 2);
        s += __shfl_xor(s, 4); s += __shfl_xor(s, 8);
        if (lr == 0) ksum[h * 256 + grow] = s;
      }
    }
}

// ---------------- fused EA GEMMs: one launch covers both
//   which=0: attn_probs = silu(ksum * (q . silu(EA@Wdk+bdk))) * cutoff(dist)
//   which=1: G = bf16(silu(EA@Wea+bea))
// 8 blocks sharing an EA row-tile (4 col-tiles x 2 matrices) pinned to one XCD.
__global__ __launch_bounds__(256, 4) void gemm_ea(const unsigned short* __restrict__ EA,
    const unsigned short* __restrict__ Wdkt, const unsigned short* __restrict__ Weat,
    const float* __restrict__ bdk, const float* __restrict__ bea,
    const float* __restrict__ qkv, const float* __restrict__ ksum,
    const float* __restrict__ dist, float* __restrict__ apout,
    unsigned short* __restrict__ G16)
{
  int b = blockIdx.x;
  int xcd = b & 7, slot = b >> 3;
  int inner = slot & 7;                 // 0..7
  int which = inner >> 2, ct = inner & 3;
  int rt = (slot >> 3) * 8 + xcd;       // 0..511
  int rbase = rt * 128, cbase = ct * 128;
  const unsigned short* Bt = which ? Weat : Wdkt;
  float4v acc[4][4];
#pragma unroll
  for (int fr = 0; fr < 4; ++fr)
#pragma unroll
    for (int fc = 0; fc < 4; ++fc) acc[fr][fc] = (float4v){0.f,0.f,0.f,0.f};
  gemm_core_b(EA, Bt, rbase, cbase, acc);

  const int t = threadIdx.x;
  const int lane = t & 63, wv = t >> 6;
  const int wr = wv >> 1, wc = wv & 1;
  const int lr = lane & 15, lk = lane >> 4;

  if (which == 0) {
    int n = rbase >> 8, mb = rbase & 255;
    int h = (cbase >> 6) + wc;
    float ks = ksum[h * 256 + n];
    float qv[4], bv[4];
#pragma unroll
    for (int fc = 0; fc < 4; ++fc) {
      int col = cbase + wc * 64 + fc * 16 + lr;
      qv[fc] = qkv[n * 1536 + col];
      bv[fc] = bdk[col];
    }
#pragma unroll
    for (int fr = 0; fr < 4; ++fr)
#pragma unroll
      for (int i = 0; i < 4; ++i) {
        float s = 0.f;
#pragma unroll
        for (int fc = 0; fc < 4; ++fc)
          s += silu_f(acc[fr][fc][i] + bv[fc]) * qv[fc];
        s += __shfl_xor(s, 1); s += __shfl_xor(s, 2);
        s += __shfl_xor(s, 4); s += __shfl_xor(s, 8);
        int m = mb + wr * 64 + fr * 16 + lk * 4 + i;
        if (lr == 0) {
          float pr = silu_f(ks * s) * cutoff_f(dist[n * 256 + m]);
          apout[h * 65536 + n * 256 + m] = pr;
        }
      }
  } else {
    float bv[4];
#pragma unroll
    for (int fc = 0; fc < 4; ++fc)
      bv[fc] = bea[cbase + wc * 64 + fc * 16 + lr];
#pragma unroll
    for (int fr = 0; fr < 4; ++fr)
#pragma unroll
      for (int i = 0; i < 4; ++i) {
        int grow = rbase + wr * 64 + fr * 16 + lk * 4 + i;
#pragma unroll
        for (int fc = 0; fc < 4; ++fc) {
          int col = cbase + wc * 64 + fc * 16 + lr;
          G16[(size_t)grow * 512 + col] = f2b(silu_f(acc[fr][fc][i] + bv[fc]));
        }
      }
  }
}

// ---------------- ipe tail: ipe[i,j,e] = G[i,j,e] * sum_c ws[i,c,e]*wt[j,c,e]
// fully coalesced; wswt (3MB) served from L2.
__global__ __launch_bounds__(256) void ipe_tail(const unsigned short* __restrict__ G16,
    const float* __restrict__ wswt, float* __restrict__ ipe)
{
  int b = blockIdx.x, t = threadIdx.x;
  int p = b * 2 + (t >> 7);            // (i,j) pair index 0..65535
  int i = p >> 8, j = p & 255;
  int col = (t & 127) * 4;
  ushort4 g = *(const ushort4*)(G16 + (size_t)p * 512 + col);
  const float* wsp = wswt + (size_t)i * 3072 + col;
  const float* wtp = wswt + (size_t)j * 3072 + 512 + col;
  float4 s = {0.f, 0.f, 0.f, 0.f};
#pragma unroll
  for (int c = 0; c < 3; ++c) {
    float4 a = *(const float4*)(wsp + c * 1024);
    float4 w = *(const float4*)(wtp + c * 1024);
    s.x += a.x * w.x; s.y += a.y * w.y; s.z += a.z * w.z; s.w += a.w * w.w;
  }
  float4 o;
  o.x = b2f(g.x) * s.x; o.y = b2f(g.y) * s.y;
  o.z = b2f(g.z) * s.z; o.w = b2f(g.w) * s.w;
  *(float4*)(ipe + (size_t)p * 512 + col) = o;
}

// ---------------- fp32 -> bf16 convert (ea + x in one launch)
__global__ __launch_bounds__(256) void cvt_bf16(const float* __restrict__ ea,
    unsigned short* __restrict__ eab, const float* __restrict__ x,
    unsigned short* __restrict__ xb)
{
  int b = blockIdx.x, t = threadIdx.x;
  const float* src; unsigned short* dst; size_t base;
  if (b < 64) { src = x;  dst = xb;  base = (size_t)b * 2048; }
  else        { src = ea; dst = eab; base = (size_t)(b - 64) * 2048; }
  size_t i = base + (size_t)t * 8;
  float4 f0 = *(const float4*)(src + i);
  float4 f1 = *(const float4*)(src + i + 4);
  uint4 o;
  o.x = pk2(f0.x, f0.y); o.y = pk2(f0.z, f0.w);
  o.z = pk2(f1.x, f1.y); o.w = pk2(f1.z, f1.w);
  *(uint4*)(dst + i) = o;
}

// ---------------- all-weights transpose + bf16: Wt[e][k] = bf16(W[k][e]), K=512
struct TJobs { const float* src[7]; unsigned short* dst[7]; int E[7]; };
__global__ __launch_bounds__(256) void transp_all(TJobs jobs)
{
  __shared__ unsigned short tl[32][36];
  int j = blockIdx.z;
  int E = jobs.E[j];
  int e0 = blockIdx.y * 32;
  if (e0 >= E) return;
  const float* W = jobs.src[j];
  unsigned short* Wt = jobs.dst[j];
  int t = threadIdx.x;
  int r = t >> 3, c4 = (t & 7) * 4;
  int k0 = blockIdx.x * 32;
  float4 f = *(const float4*)(W + (size_t)(k0 + r) * E + e0 + c4);
  tl[c4 + 0][r] = f2b(f.x);
  tl[c4 + 1][r] = f2b(f.y);
  tl[c4 + 2][r] = f2b(f.z);
  tl[c4 + 3][r] = f2b(f.w);
  __syncthreads();
  uint2 o;
  o.x = (unsigned int)tl[r][c4] | ((unsigned int)tl[r][c4 + 1] << 16);
  o.y = (unsigned int)tl[r][c4 + 2] | ((unsigned int)tl[r][c4 + 3] << 16);
  *(uint2*)(Wt + (size_t)(e0 + r) * 512 + k0 + c4) = o;
}

// ---------------- stage C: attn out, Z bf16 [n][c][e], vsum[n][c]
__global__ __launch_bounds__(512) void stage_c(const float* __restrict__ ap,
    const float* __restrict__ qkv, const float* __restrict__ vec,
    float* __restrict__ attn_out, unsigned short* __restrict__ Z16,
    float* __restrict__ vsum)
{
  __shared__ float aps[2048];    // [h][m]
  __shared__ float vecs[768];    // [c][m]
  int n = blockIdx.x, t = threadIdx.x;
  for (int i = t; i < 2048; i += 512) {
    int h = i >> 8, m = i & 255;
    aps[i] = ap[h * 65536 + n * 256 + m];
  }
  for (int i = t; i < 768; i += 512) {
    int m = i / 3, c = i - 3 * m;
    vecs[c * 256 + m] = vec[(n * 256 + m) * 3 + c];
  }
  __syncthreads();
  int h = t >> 6;
  const float* apn_row = aps + h * 256;
  const float* vrow = qkv + 1024 + t;
  float a_acc = 0.f, z0 = 0.f, z1 = 0.f, z2 = 0.f;
#pragma unroll 4
  for (int m = 0; m < 256; ++m) {
    float p = apn_row[m];
    float vl = vrow[(size_t)m * 1536];
    float pv = p * vl;
    a_acc += pv;
    z0 += vecs[m] * pv;
    z1 += vecs[256 + m] * pv;
    z2 += vecs[512 + m] * pv;
  }
  attn_out[n * 512 + t] = a_acc;
  Z16[(n * 3 + 0) * 512 + t] = f2b(z0);
  Z16[(n * 3 + 1) * 512 + t] = f2b(z1);
  Z16[(n * 3 + 2) * 512 + t] = f2b(z2);
  if (t < 3) {
    float s = 0.f;
    for (int m = 0; m < 256; ++m) s += vecs[t * 256 + m];
    vsum[n * 3 + t] = s;
  }
}

// ---------------- vec layer norm max-min: du fp32 (N,3,E) -> du16 bf16
__global__ __launch_bounds__(512) void vecnorm(const float* __restrict__ du,
                                               unsigned short* __restrict__ du16)
{
  __shared__ float smx[8], smn[8];
  int n = blockIdx.x, t = threadIdx.x;
  float d0 = du[(n * 3 + 0) * 512 + t];
  float d1 = du[(n * 3 + 1) * 512 + t];
  float d2 = du[(n * 3 + 2) * 512 + t];
  float norm = sqrtf(d0 * d0 + d1 * d1 + d2 * d2);
  norm = fmaxf(norm, 1e-12f);
  float mx = norm, mn = norm;
#pragma unroll
  for (int o = 1; o < 64; o <<= 1) {
    mx = fmaxf(mx, __shfl_xor(mx, o));
    mn = fminf(mn, __shfl_xor(mn, o));
  }
  if ((t & 63) == 0) { smx[t >> 6] = mx; smn[t >> 6] = mn; }
  __syncthreads();
  float gmx = smx[0], gmn = smn[0];
#pragma unroll
  for (int i = 1; i < 8; ++i) { gmx = fmaxf(gmx, smx[i]); gmn = fminf(gmn, smn[i]); }
  float delta = gmx - gmn;
  if (delta == 0.0f) delta = 1.0f;
  float dn = fmaxf((norm - gmn) / delta, 0.0f);
  float sc = dn / norm;
  du16[(n * 3 + 0) * 512 + t] = f2b(d0 * sc);
  du16[(n * 3 + 1) * 512 + t] = f2b(d1 * sc);
  du16[(n * 3 + 2) * 512 + t] = f2b(d2 * sc);
}

extern "C" void kernel_launch(void* const* d_in, const int* in_sizes, int n_in,
                              void* d_out, int out_size, void* d_ws, size_t ws_size,
                              hipStream_t stream)
{
  const float* x    = (const float*)d_in[0];
  const float* vec  = (const float*)d_in[1];
  const float* dist = (const float*)d_in[2];
  const float* ea   = (const float*)d_in[3];
  const float* Wq   = (const float*)d_in[4];
  const float* bq   = (const float*)d_in[5];
  const float* Wk   = (const float*)d_in[6];
  const float* bk   = (const float*)d_in[7];
  const float* Wv   = (const float*)d_in[8];
  const float* bv   = (const float*)d_in[9];
  const float* Wdk  = (const float*)d_in[10];
  const float* bdk  = (const float*)d_in[11];
  const float* Wdu  = (const float*)d_in[12];
  const float* bdu  = (const float*)d_in[13];
  const float* Wdih = (const float*)d_in[14];
  const float* Wea  = (const float*)d_in[15];
  const float* bea  = (const float*)d_in[16];
  float* out_attn = (float*)d_out;
  float* out_ipe  = out_attn + 256 * 512;

  unsigned short* eab    = (unsigned short*)d_ws;       // 33554432
  unsigned short* G16    = eab + 33554432;              // 33554432
  unsigned short* xb     = G16 + 33554432;              // 131072
  unsigned short* Wqkv_t = xb + 131072;                 // 786432
  unsigned short* Wdk_t  = Wqkv_t + 786432;             // 262144
  unsigned short* Wdu_t  = Wdk_t + 262144;              // 262144
  unsigned short* Wea_t  = Wdu_t + 262144;              // 262144
  unsigned short* Wdih_t = Wea_t + 262144;              // 524288
  unsigned short* Z16    = Wdih_t + 524288;             // 393216
  unsigned short* du16   = Z16 + 393216;                // 393216
  float* fbase = (float*)(du16 + 393216);
  float* qkvb  = fbase;            // 256*1536
  float* ksumb = qkvb + 393216;    // 2048
  float* apb   = ksumb + 2048;     // 524288
  float* vsumb = apb + 524288;     // 768
  float* dub   = vsumb + 768;      // 393216
  float* wswtb = dub + 393216;     // 786432

  dim3 b256(256), b512(512);

  cvt_bf16<<<16448, b256, 0, stream>>>(ea, eab, x, xb);

  TJobs jobs;
  jobs.src[0] = Wq;   jobs.dst[0] = Wqkv_t;           jobs.E[0] = 512;
  jobs.src[1] = Wk;   jobs.dst[1] = Wqkv_t + 262144;  jobs.E[1] = 512;
  jobs.src[2] = Wv;   jobs.dst[2] = Wqkv_t + 524288;  jobs.E[2] = 512;
  jobs.src[3] = Wdk;  jobs.dst[3] = Wdk_t;            jobs.E[3] = 512;
  jobs.src[4] = Wdu;  jobs.dst[4] = Wdu_t;            jobs.E[4] = 512;
  jobs.src[5] = Wea;  jobs.dst[5] = Wea_t;            jobs.E[5] = 512;
  jobs.src[6] = Wdih; jobs.dst[6] = Wdih_t;           jobs.E[6] = 1024;
  transp_all<<<dim3(16, 32, 7), b256, 0, stream>>>(jobs);

  gemm_qkv<<<24, b256, 0, stream>>>(xb, Wqkv_t, bq, bk, bv, qkvb, ksumb);
  gemm_ea<<<4096, b256, 0, stream>>>(eab, Wdk_t, Wea_t, bdk, bea, qkvb, ksumb,
                                     dist, apb, G16);
  stage_c<<<256, b512, 0, stream>>>(apb, qkvb, vec, out_attn, Z16, vsumb);
  gemm_lin<<<24, b256, 0, stream>>>(Z16, Wdu_t, bdu, vsumb, dub, 512, 4);
  vecnorm<<<256, b512, 0, stream>>>(dub, du16);
  gemm_lin<<<48, b256, 0, stream>>>(du16, Wdih_t, nullptr, nullptr, wswtb, 1024, 8);
  ipe_tail<<<32768, b256, 0, stream>>>(G16, wswtb, out_ipe);
}